// Round 1
// baseline (18.395 us; speedup 1.0000x reference)
//
#include <hip/hip_runtime.h>
#include <math.h>

#define BATCH 2048
#define IN_DIM 784
#define NQ 14
#define NF 105
#define NC 10

// Analytic collapse of the quantum feature map:
//   angles  = tanh(x @ proj_w.T + proj_b) * pi          (B, 14)
//   c_q     = cos(angle_q)
//   final bit k of circuit = XOR of initial bits {k, k-2, k-4, ...}
//   <Z_i>    = prod_{q in S_i} c_q,  S_i = {i, i-2, ...}
//   <Z_i Z_j>= prod over S_i XOR S_j
//   out      = feats @ cls_w.T + cls_b
// Mask closed form: zm(q) = (0x1555 << (q&1)) & ((2u<<q)-1)

__device__ __forceinline__ unsigned zmask(int q) {
    return (0x1555u << (q & 1)) & ((2u << q) - 1u);
}

__global__ __launch_bounds__(256) void qfm_kernel(
    const float* __restrict__ x,
    const float* __restrict__ pw,
    const float* __restrict__ pb,
    const float* __restrict__ cw,
    const float* __restrict__ cb,
    float* __restrict__ out)
{
    const int wave = (int)((blockIdx.x * blockDim.x + threadIdx.x) >> 6);
    const int lane = (int)(threadIdx.x & 63);
    if (wave >= BATCH) return;

    // ---- load x row as float4 chunks (196 float4 per row) ----
    const float4* xr4 = reinterpret_cast<const float4*>(x + (size_t)wave * IN_DIM);
    float4 xv[3];
#pragma unroll
    for (int k = 0; k < 3; ++k) xv[k] = xr4[lane + 64 * k];
    float4 xrem = make_float4(0.f, 0.f, 0.f, 0.f);
    if (lane < 4) xrem = xr4[192 + lane];

    // ---- 14 projection dot products -> cos(theta_q), all lanes get all 14 ----
    float c[NQ];
#pragma unroll
    for (int q = 0; q < NQ; ++q) {
        const float4* wr4 = reinterpret_cast<const float4*>(pw + (size_t)q * IN_DIM);
        float acc = 0.f;
#pragma unroll
        for (int k = 0; k < 3; ++k) {
            float4 wv = wr4[lane + 64 * k];
            acc += xv[k].x * wv.x + xv[k].y * wv.y + xv[k].z * wv.z + xv[k].w * wv.w;
        }
        if (lane < 4) {
            float4 wv = wr4[192 + lane];
            acc += xrem.x * wv.x + xrem.y * wv.y + xrem.z * wv.z + xrem.w * wv.w;
        }
        // wave-wide butterfly reduce (all lanes end with the full sum)
#pragma unroll
        for (int s = 32; s > 0; s >>= 1) acc += __shfl_xor(acc, s, 64);
        float theta = tanhf(acc + pb[q]) * 3.14159265358979323846f;
        c[q] = cosf(theta);
    }

    // ---- features: lane handles f = lane and f = lane + 64 ----
    float acc_out[NC];
#pragma unroll
    for (int k = 0; k < NC; ++k) acc_out[k] = 0.f;

#pragma unroll
    for (int rep = 0; rep < 2; ++rep) {
        const int f = lane + rep * 64;
        if (f < NF) {
            unsigned m;
            if (f < NQ) {
                m = zmask(f);
            } else {
                int g = f - NQ;
                int i = 0;
                while (g >= NQ - 1 - i) { g -= NQ - 1 - i; ++i; }
                const int j = i + 1 + g;
                m = zmask(i) ^ zmask(j);
            }
            float prod = 1.f;
#pragma unroll
            for (int q = 0; q < NQ; ++q) {
                const float mult = ((m >> q) & 1u) ? c[q] : 1.0f;
                prod *= mult;
            }
#pragma unroll
            for (int k = 0; k < NC; ++k)
                acc_out[k] += cw[k * NF + f] * prod;
        }
    }

    // ---- reduce 10 outputs across the wave, lane 0 writes ----
#pragma unroll
    for (int k = 0; k < NC; ++k) {
        float a = acc_out[k];
#pragma unroll
        for (int s = 32; s > 0; s >>= 1) a += __shfl_xor(a, s, 64);
        if (lane == 0) out[(size_t)wave * NC + k] = a + cb[k];
    }
}

extern "C" void kernel_launch(void* const* d_in, const int* in_sizes, int n_in,
                              void* d_out, int out_size, void* d_ws, size_t ws_size,
                              hipStream_t stream) {
    const float* x  = (const float*)d_in[0];
    const float* pw = (const float*)d_in[1];
    const float* pb = (const float*)d_in[2];
    const float* cw = (const float*)d_in[3];
    const float* cb = (const float*)d_in[4];
    float* out = (float*)d_out;

    const int waves_per_block = 256 / 64;               // 4 rows per block
    const int blocks = BATCH / waves_per_block;         // 512
    qfm_kernel<<<dim3(blocks), dim3(256), 0, stream>>>(x, pw, pb, cw, cb, out);
}